// Round 17
// baseline (6185.128 us; speedup 1.0000x reference)
//
#include <hip/hip_runtime.h>
#include <cstdint>
#include <cstddef>

#define HD   1024
#define SEQL 200
#define MEMN 50
#define RTOT 51200   // 256 * 200
#define PK   72      // fHi/fLo row stride (64 + 8 pad -> 2-way banks, free)

typedef float  f4    __attribute__((ext_vector_type(4)));
typedef float  f32x4 __attribute__((ext_vector_type(4)));
typedef short  s16x8 __attribute__((ext_vector_type(8)));
typedef unsigned short u16;
typedef unsigned short u16x4 __attribute__((ext_vector_type(4)));
typedef unsigned short u16x8 __attribute__((ext_vector_type(8)));

__device__ __forceinline__ u16 f2bf(float f) {
    unsigned u = __builtin_bit_cast(unsigned, f);
    u += 0x7FFFu + ((u >> 16) & 1u);          // RNE
    return (u16)(u >> 16);
}
__device__ __forceinline__ float bf2f(u16 h) {
    unsigned u = ((unsigned)h) << 16;
    return __builtin_bit_cast(float, u);
}

#define GLOAD_LDS16(g, l) __builtin_amdgcn_global_load_lds( \
    (const __attribute__((address_space(1))) unsigned int*)(g), \
    (__attribute__((address_space(3))) unsigned int*)(l), 16, 0, 0)

#define WAITV2 asm volatile("s_waitcnt vmcnt(2)" ::: "memory")
#define WAITV0 asm volatile("s_waitcnt vmcnt(0)" ::: "memory")
#define LGKMFENCE asm volatile("s_waitcnt lgkmcnt(0)" ::: "memory")
#define SCHB   __builtin_amdgcn_sched_barrier(0)

// ---------------------------------------------------------------------------
// K0a: gate_w f32 -> bf16 gwB [o][2048] k-contig. Wf = cols 0..1023,
//      Wm = cols 1024..2047.
// ---------------------------------------------------------------------------
__global__ __launch_bounds__(256) void k_cvt_w(const float* __restrict__ gw,
                                               u16* __restrict__ gwB)
{
    const size_t i = ((size_t)blockIdx.x * 256 + threadIdx.x) * 8;
    f4 v0 = *(const f4*)&gw[i];
    f4 v1 = *(const f4*)&gw[i + 4];
    u16x4 b0 = { f2bf(v0.x), f2bf(v0.y), f2bf(v0.z), f2bf(v0.w) };
    u16x4 b1 = { f2bf(v1.x), f2bf(v1.y), f2bf(v1.z), f2bf(v1.w) };
    *(u16x4*)&gwB[i]     = b0;
    *(u16x4*)&gwB[i + 4] = b1;
}

// ---------------------------------------------------------------------------
// K0b: spatial memory prep (round-13).
// ---------------------------------------------------------------------------
__global__ __launch_bounds__(256) void k_prep_mem(const float* __restrict__ sm,
                                                  u16* __restrict__ memHi,
                                                  u16* __restrict__ memT,
                                                  u16* __restrict__ memSH,
                                                  u16* __restrict__ memSL)
{
    const int idx = blockIdx.x * 256 + threadIdx.x;   // 16384 total
    const int m  = idx >> 8;
    const int h0 = (idx & 255) * 4;
    f4 v = {0.f, 0.f, 0.f, 0.f};
    if (m < MEMN) v = *(const f4*)&sm[(size_t)m * HD + h0];
    u16x4 hi = { f2bf(v.x), f2bf(v.y), f2bf(v.z), f2bf(v.w) };
    f4 hv = { bf2f(hi.x), bf2f(hi.y), bf2f(hi.z), bf2f(hi.w) };
    f4 lv = v - hv;
    u16x4 lo = { f2bf(lv.x), f2bf(lv.y), f2bf(lv.z), f2bf(lv.w) };
    *(u16x4*)&memHi[(size_t)m * HD + h0] = hi;
    memT[(size_t)(h0 + 0) * 64 + m] = hi.x;
    memT[(size_t)(h0 + 1) * 64 + m] = hi.y;
    memT[(size_t)(h0 + 2) * 64 + m] = hi.z;
    memT[(size_t)(h0 + 3) * 64 + m] = hi.w;
    const int p = h0 >> 6, s = (h0 >> 3) & 7, e = h0 & 7;
    const size_t sw = (size_t)p * 4096 + m * 64 + ((s ^ (m & 7)) << 3) + e;
    *(u16x4*)&memSH[sw] = hi;
    *(u16x4*)&memSL[sw] = lo;
}

// ---------------------------------------------------------------------------
// K0d: MWmT[o][m] = (M @ Wm)(m,o) as bf16, [1024][64].  MFMA, 16 blocks.
// ---------------------------------------------------------------------------
__global__ __launch_bounds__(256) void k_mwm(const u16* __restrict__ memHi,
                                             const u16* __restrict__ gwB,
                                             u16* __restrict__ MWmT)
{
    const int tid = threadIdx.x, lane = tid & 63, w = tid >> 6;
    const int fr = lane & 15, fk = (lane >> 4) * 8, jr = (lane >> 4) * 4;
    const int ob = blockIdx.x * 64 + w * 16;       // o-base of this wave
    f32x4 acc[4] = {};
    for (int ks = 0; ks < 32; ++ks) {
        s16x8 b = *(const s16x8*)&gwB[(size_t)(ob + fr) * 2048 + 1024 + ks * 32 + fk];
        #pragma unroll
        for (int mt = 0; mt < 4; ++mt) {
            s16x8 a = *(const s16x8*)&memHi[(size_t)(mt * 16 + fr) * HD + ks * 32 + fk];
            acc[mt] = __builtin_amdgcn_mfma_f32_16x16x32_bf16(a, b, acc[mt], 0, 0, 0);
        }
    }
    #pragma unroll
    for (int mt = 0; mt < 4; ++mt)
        #pragma unroll
        for (int j = 0; j < 4; ++j)
            MWmT[(size_t)(ob + fr) * 64 + mt * 16 + jr + j] = f2bf(acc[mt][j]);
}

// ---------------------------------------------------------------------------
// K1: round-13 fused feats+sim+softmax (vmem-free MFMA section).
// ---------------------------------------------------------------------------
__global__ __launch_bounds__(256) void k_pre(
    const float* __restrict__ x, const float* __restrict__ pos,
    const u16* __restrict__ memSH, const u16* __restrict__ memSL,
    u16* __restrict__ featsB, u16* __restrict__ wBg)
{
    __shared__ u16 fHi[64 * PK];
    __shared__ u16 fLo[64 * PK];
    __shared__ u16 memH[2][64 * 64];
    __shared__ u16 memL[2][64 * 64];

    const int tid  = threadIdx.x;
    const int r0   = blockIdx.x * 64;
    const int lane = tid & 63, w = tid >> 6;
    const int fr   = lane & 15, sg = lane >> 4;
    const int fk   = sg * 8, jr = sg * 4;

    const int srow = tid >> 2;
    const int scol = (tid & 3) * 16;
    const int prow = (r0 + srow) % SEQL;
    const float* xrow = &x[(size_t)(r0 + srow) * HD];
    const float* prp  = &pos[(size_t)prow * HD];

    f4 xa[4], pa[4];
    #pragma unroll
    for (int i = 0; i < 4; ++i) {
        xa[i] = *(const f4*)&xrow[scol + i * 4];
        pa[i] = *(const f4*)&prp[scol + i * 4];
    }
    GLOAD_LDS16(memSH + tid * 8,        &memH[0][tid * 8]);
    GLOAD_LDS16(memSH + 2048 + tid * 8, &memH[0][2048 + tid * 8]);
    GLOAD_LDS16(memSL + tid * 8,        &memL[0][tid * 8]);
    GLOAD_LDS16(memSL + 2048 + tid * 8, &memL[0][2048 + tid * 8]);

    f32x4 acc[4] = {};

    for (int p = 0; p < 16; ++p) {
        const int b = p & 1;
        WAITV0;

        {
            f4 f0 = xa[0] + pa[0], f1 = xa[1] + pa[1];
            f4 f2 = xa[2] + pa[2], f3 = xa[3] + pa[3];
            u16x8 h0 = { f2bf(f0.x), f2bf(f0.y), f2bf(f0.z), f2bf(f0.w),
                         f2bf(f1.x), f2bf(f1.y), f2bf(f1.z), f2bf(f1.w) };
            u16x8 h1 = { f2bf(f2.x), f2bf(f2.y), f2bf(f2.z), f2bf(f2.w),
                         f2bf(f3.x), f2bf(f3.y), f2bf(f3.z), f2bf(f3.w) };
            *(u16x8*)&featsB[(size_t)(r0 + srow) * HD + p * 64 + scol]     = h0;
            *(u16x8*)&featsB[(size_t)(r0 + srow) * HD + p * 64 + scol + 8] = h1;
            f4 hv0 = { bf2f(h0[0]), bf2f(h0[1]), bf2f(h0[2]), bf2f(h0[3]) };
            f4 hv1 = { bf2f(h0[4]), bf2f(h0[5]), bf2f(h0[6]), bf2f(h0[7]) };
            f4 hv2 = { bf2f(h1[0]), bf2f(h1[1]), bf2f(h1[2]), bf2f(h1[3]) };
            f4 hv3 = { bf2f(h1[4]), bf2f(h1[5]), bf2f(h1[6]), bf2f(h1[7]) };
            f4 l0 = f0 - hv0, l1 = f1 - hv1, l2 = f2 - hv2, l3 = f3 - hv3;
            u16x8 lo0 = { f2bf(l0.x), f2bf(l0.y), f2bf(l0.z), f2bf(l0.w),
                          f2bf(l1.x), f2bf(l1.y), f2bf(l1.z), f2bf(l1.w) };
            u16x8 lo1 = { f2bf(l2.x), f2bf(l2.y), f2bf(l2.z), f2bf(l2.w),
                          f2bf(l3.x), f2bf(l3.y), f2bf(l3.z), f2bf(l3.w) };
            *(u16x8*)&fHi[srow * PK + scol]     = h0;
            *(u16x8*)&fHi[srow * PK + scol + 8] = h1;
            *(u16x8*)&fLo[srow * PK + scol]     = lo0;
            *(u16x8*)&fLo[srow * PK + scol + 8] = lo1;
        }
        LGKMFENCE;
        __builtin_amdgcn_s_barrier();

        if (p < 15) {
            const size_t mo = (size_t)(p + 1) * 4096;
            GLOAD_LDS16(memSH + mo + tid * 8,        &memH[b ^ 1][tid * 8]);
            GLOAD_LDS16(memSH + mo + 2048 + tid * 8, &memH[b ^ 1][2048 + tid * 8]);
            GLOAD_LDS16(memSL + mo + tid * 8,        &memL[b ^ 1][tid * 8]);
            GLOAD_LDS16(memSL + mo + 2048 + tid * 8, &memL[b ^ 1][2048 + tid * 8]);
            const int c = (p + 1) * 64 + scol;
            #pragma unroll
            for (int i = 0; i < 4; ++i) {
                xa[i] = *(const f4*)&xrow[c + i * 4];
                pa[i] = *(const f4*)&prp[c + i * 4];
            }
        }

        #pragma unroll
        for (int ks = 0; ks < 2; ++ks) {
            s16x8 aH = *(const s16x8*)&fHi[(16 * w + fr) * PK + ks * 32 + fk];
            s16x8 aL = *(const s16x8*)&fLo[(16 * w + fr) * PK + ks * 32 + fk];
            #pragma unroll
            for (int n = 0; n < 4; ++n) {
                const int m = n * 16 + fr;
                const int slot = ((ks * 4 + sg) ^ (m & 7)) * 8;
                s16x8 bH = *(const s16x8*)&memH[b][m * 64 + slot];
                s16x8 bL = *(const s16x8*)&memL[b][m * 64 + slot];
                acc[n] = __builtin_amdgcn_mfma_f32_16x16x32_bf16(aH, bH, acc[n], 0, 0, 0);
                acc[n] = __builtin_amdgcn_mfma_f32_16x16x32_bf16(aH, bL, acc[n], 0, 0, 0);
                acc[n] = __builtin_amdgcn_mfma_f32_16x16x32_bf16(aL, bH, acc[n], 0, 0, 0);
            }
        }
    }

    // softmax over m (50)
    #pragma unroll
    for (int j = 0; j < 4; ++j) {
        const int rg = r0 + 16 * w + jr + j;
        float v[4];
        float mx = -1e30f;
        #pragma unroll
        for (int n = 0; n < 4; ++n) {
            v[n] = acc[n][j];
            const int m = n * 16 + fr;
            if (m < MEMN) mx = fmaxf(mx, v[n]);
        }
        #pragma unroll
        for (int d = 1; d < 16; d <<= 1) mx = fmaxf(mx, __shfl_xor(mx, d));
        float e[4], s = 0.f;
        #pragma unroll
        for (int n = 0; n < 4; ++n) {
            const int m = n * 16 + fr;
            e[n] = (m < MEMN) ? __expf(v[n] - mx) : 0.f;
            s += e[n];
        }
        #pragma unroll
        for (int d = 1; d < 16; d <<= 1) s += __shfl_xor(s, d);
        const float inv = 1.f / s;
        #pragma unroll
        for (int n = 0; n < 4; ++n)
            wBg[(size_t)rg * 64 + n * 16 + fr] = f2bf(e[n] * inv); // 0 pad m>=50
    }
}

// ---------------------------------------------------------------------------
// K2: out = featsB + sigmoid([featsB|w]@[Wf;MWm] + b) * (w@M).
//     Round-16 4-phase reg-staged schedule at BK=32: 34 tiles x 2 phases.
//     BM=BN=256, 8 waves (2Mx4N, per-wave 128x64, acc[8][4]).
//     LDS = 64 KB (2x16 A + 2x16 B) -> 2 blocks/CU, 16 waves/CU.
//     Counted WAITV2 every phase (retire distance 2 phases); loads of tile
//     T+2 issued at tile T; ds_writes of tile T+1 at tile T (2-phase
//     write-to-use gap, race-free vs buf^1). B-frags read once per tile,
//     register-reused across both m-halves. Never vmcnt(0) mid-loop.
// ---------------------------------------------------------------------------
__global__ __launch_bounds__(512, 4) void k_gate_out(
    const u16* __restrict__ featsB, const u16* __restrict__ wBg,
    const u16* __restrict__ gwB, const u16* __restrict__ memT,
    const u16* __restrict__ MWmT, const float* __restrict__ gb,
    float* __restrict__ out)
{
    __shared__ u16 As[2][256 * 32];   // 2 x 16 KB
    __shared__ u16 Bs[2][256 * 32];   // 2 x 16 KB  (total 64 KB)

    const int tid = threadIdx.x;
    int bid = blockIdx.x;
    bid = (bid & 7) * 100 + (bid >> 3);      // XCD swizzle (800 % 8 == 0)
    const int mt = bid >> 2, nt = bid & 3;   // 200 x 4 tiles
    const int row0 = mt * 256, col0 = nt * 256;
    const int lane = tid & 63, wave = tid >> 6;
    const int wm = wave >> 2, wn = wave & 3; // 2M x 4N (128x64 each)
    const int fr = lane & 15, sg = lane >> 4;
    const int fk = sg * 8;

    f32x4 acc[8][4] = {};
    s16x8 aF[4], bF[4];
    s16x8 rA[2][2], rB[2][2];                // [tile parity][j]

    const int srow = tid >> 1;               // staging row 0..255
    const int sl0  = (tid & 1) * 2;          // first of 2 16B slots

    auto loadA = [&](int kt, s16x8 r[2]) {
        #pragma unroll
        for (int j = 0; j < 2; ++j) {
            const int sl = sl0 + j;
            const u16* p = (kt < 32)
              ? featsB + (size_t)(row0 + srow) * HD + kt * 32 + sl * 8
              : wBg    + (size_t)(row0 + srow) * 64 + (kt - 32) * 32 + sl * 8;
            r[j] = *(const s16x8*)p;
        }
    };
    auto loadB = [&](int kt, s16x8 r[2]) {
        #pragma unroll
        for (int j = 0; j < 2; ++j) {
            const int sl = sl0 + j;
            const u16* p = (kt < 32)
              ? gwB  + (size_t)(col0 + srow) * 2048 + kt * 32 + sl * 8
              : MWmT + (size_t)(col0 + srow) * 64 + (kt - 32) * 32 + sl * 8;
            r[j] = *(const s16x8*)p;
        }
    };
    auto writeU = [&](u16* base, s16x8 r[2]) {
        #pragma unroll
        for (int j = 0; j < 2; ++j) {
            const int sl = sl0 + j;
            const int slot = sl ^ (srow & 3);
            *(s16x8*)&base[srow * 32 + slot * 8] = r[j];
        }
    };

    // prologue: tile 0 staged + written; tile 1 loads in flight.
    loadA(0, rA[0]); loadB(0, rB[0]);
    WAITV0;
    writeU(&As[0][0], rA[0]); writeU(&Bs[0][0], rB[0]);
    loadA(1, rA[1]); loadB(1, rB[1]);        // 4 outstanding
    LGKMFENCE;
    __builtin_amdgcn_s_barrier();            // tile 0 published

    for (int T = 0; T < 34; ++T) {
        const int buf = T & 1;
        const int pn  = (T + 1) & 1;         // regs holding tile T+1
        const int p2  = T & 1;               // regs to receive tile T+2

        // ================= phase 0: m-half 0 (m = 0..3) =================
        #pragma unroll
        for (int i = 0; i < 4; ++i) {
            const int r_ = wm * 128 + i * 16 + fr;
            aF[i] = *(const s16x8*)&As[buf][r_ * 32 + (sg ^ (r_ & 3)) * 8];
        }
        #pragma unroll
        for (int n = 0; n < 4; ++n) {
            const int c_ = wn * 64 + n * 16 + fr;
            bF[n] = *(const s16x8*)&Bs[buf][c_ * 32 + (sg ^ (c_ & 3)) * 8];
        }
        if (T + 2 < 34) { loadA(T + 2, rA[p2]); WAITV2; }
        else if (T == 32) { WAITV0; }        // retire B(33)
        if (T + 1 < 34) writeU(&As[buf ^ 1][0], rA[pn]);
        __builtin_amdgcn_s_barrier();
        LGKMFENCE;
        SCHB;
        __builtin_amdgcn_s_setprio(1);
        #pragma unroll
        for (int i = 0; i < 4; ++i)
            #pragma unroll
            for (int n = 0; n < 4; ++n)
                acc[i][n] = __builtin_amdgcn_mfma_f32_16x16x32_bf16(
                    aF[i], bF[n], acc[i][n], 0, 0, 0);
        __builtin_amdgcn_s_setprio(0);
        __builtin_amdgcn_s_barrier();

        // ================= phase 1: m-half 1 (m = 4..7) =================
        #pragma unroll
        for (int i = 0; i < 4; ++i) {
            const int r_ = wm * 128 + (4 + i) * 16 + fr;
            aF[i] = *(const s16x8*)&As[buf][r_ * 32 + (sg ^ (r_ & 3)) * 8];
        }
        if (T + 2 < 34) { loadB(T + 2, rB[p2]); WAITV2; }
        if (T + 1 < 34) writeU(&Bs[buf ^ 1][0], rB[pn]);
        __builtin_amdgcn_s_barrier();
        LGKMFENCE;
        SCHB;
        __builtin_amdgcn_s_setprio(1);
        #pragma unroll
        for (int i = 0; i < 4; ++i)
            #pragma unroll
            for (int n = 0; n < 4; ++n)
                acc[4 + i][n] = __builtin_amdgcn_mfma_f32_16x16x32_bf16(
                    aF[i], bF[n], acc[4 + i][n], 0, 0, 0);
        __builtin_amdgcn_s_setprio(0);
        __builtin_amdgcn_s_barrier();
    }

    // epilogue: accR = w@M per (m,n); out = feats + sigmoid(acc+b)*accR
    #pragma unroll
    for (int m = 0; m < 8; ++m) {
        const size_t ab = (size_t)(row0 + wm * 128 + m * 16 + fr) * 64 + fk;
        s16x8 a2_0 = *(const s16x8*)&wBg[ab];
        s16x8 a2_1 = *(const s16x8*)&wBg[ab + 32];
        #pragma unroll
        for (int n = 0; n < 4; ++n) {
            const size_t cb = (size_t)(col0 + wn * 64 + n * 16 + fr) * 64 + fk;
            s16x8 bT0 = *(const s16x8*)&memT[cb];
            s16x8 bT1 = *(const s16x8*)&memT[cb + 32];
            f32x4 accR = {};
            accR = __builtin_amdgcn_mfma_f32_16x16x32_bf16(a2_0, bT0, accR, 0, 0, 0);
            accR = __builtin_amdgcn_mfma_f32_16x16x32_bf16(a2_1, bT1, accR, 0, 0, 0);

            const int crow = row0 + wm * 128 + m * 16 + sg * 4;
            const int ccol = col0 + wn * 64 + n * 16 + fr;
            const float bias = gb[ccol];
            #pragma unroll
            for (int j = 0; j < 4; ++j) {
                const size_t idx = (size_t)(crow + j) * HD + ccol;
                const float fe = bf2f(featsB[idx]);
                const float pre = acc[m][n][j] + bias;
                const float g = 1.0f / (1.0f + __expf(-pre));
                out[idx] = fe + g * accR[j];
            }
        }
    }
}

// ---------------------------------------------------------------------------
extern "C" void kernel_launch(void* const* d_in, const int* in_sizes, int n_in,
                              void* d_out, int out_size, void* d_ws, size_t ws_size,
                              hipStream_t stream)
{
    const float* x   = (const float*)d_in[0];
    const float* sm  = (const float*)d_in[1];
    const float* pos = (const float*)d_in[2];
    const float* gw  = (const float*)d_in[3];
    const float* gb  = (const float*)d_in[4];
    float* out = (float*)d_out;

    u16* featsB = (u16*)d_ws;                          // 51200*1024 (100 MB)
    u16* gwB    = featsB + (size_t)RTOT * HD;          // 1024*2048
    u16* wBg    = gwB + (size_t)HD * 2048;             // 51200*64
    u16* memHi  = wBg + (size_t)RTOT * 64;             // 64*1024
    u16* memT   = memHi + 64 * HD;                     // 1024*64
    u16* MWmT   = memT + (size_t)HD * 64;              // 1024*64
    u16* memSH  = MWmT + (size_t)HD * 64;              // 16*64*64 swizzled
    u16* memSL  = memSH + (size_t)64 * HD;             // 16*64*64 swizzled

    k_cvt_w<<<dim3(1024), dim3(256), 0, stream>>>(gw, gwB);
    k_prep_mem<<<dim3(64), dim3(256), 0, stream>>>(sm, memHi, memT, memSH, memSL);
    k_mwm<<<dim3(16), dim3(256), 0, stream>>>(memHi, gwB, MWmT);
    k_pre<<<dim3(RTOT / 64), dim3(256), 0, stream>>>(x, pos, memSH, memSL,
                                                     featsB, wBg);
    k_gate_out<<<dim3(800), dim3(512), 0, stream>>>(featsB, wBg, gwB, memT,
                                                    MWmT, gb, out);
}

// Round 18
// 415.636 us; speedup vs baseline: 14.8811x; 14.8811x over previous
//
#include <hip/hip_runtime.h>
#include <cstdint>
#include <cstddef>

#define HD   1024
#define SEQL 200
#define MEMN 50
#define RTOT 51200   // 256 * 200
#define PK   72      // fHi/fLo row stride (64 + 8 pad -> 2-way banks, free)

typedef float  f4    __attribute__((ext_vector_type(4)));
typedef float  f32x4 __attribute__((ext_vector_type(4)));
typedef short  s16x8 __attribute__((ext_vector_type(8)));
typedef unsigned short u16;
typedef unsigned short u16x4 __attribute__((ext_vector_type(4)));
typedef unsigned short u16x8 __attribute__((ext_vector_type(8)));

__device__ __forceinline__ u16 f2bf(float f) {
    unsigned u = __builtin_bit_cast(unsigned, f);
    u += 0x7FFFu + ((u >> 16) & 1u);          // RNE
    return (u16)(u >> 16);
}
__device__ __forceinline__ float bf2f(u16 h) {
    unsigned u = ((unsigned)h) << 16;
    return __builtin_bit_cast(float, u);
}

#define GLOAD_LDS16(g, l) __builtin_amdgcn_global_load_lds( \
    (const __attribute__((address_space(1))) unsigned int*)(g), \
    (__attribute__((address_space(3))) unsigned int*)(l), 16, 0, 0)

#define WAITV0 asm volatile("s_waitcnt vmcnt(0)" ::: "memory")
#define LGKMFENCE asm volatile("s_waitcnt lgkmcnt(0)" ::: "memory")
#define SCHB   __builtin_amdgcn_sched_barrier(0)

// ---------------------------------------------------------------------------
// K0a: gate_w f32 -> bf16 gwB [o][2048] k-contig. Wf = cols 0..1023,
//      Wm = cols 1024..2047.
// ---------------------------------------------------------------------------
__global__ __launch_bounds__(256) void k_cvt_w(const float* __restrict__ gw,
                                               u16* __restrict__ gwB)
{
    const size_t i = ((size_t)blockIdx.x * 256 + threadIdx.x) * 8;
    f4 v0 = *(const f4*)&gw[i];
    f4 v1 = *(const f4*)&gw[i + 4];
    u16x4 b0 = { f2bf(v0.x), f2bf(v0.y), f2bf(v0.z), f2bf(v0.w) };
    u16x4 b1 = { f2bf(v1.x), f2bf(v1.y), f2bf(v1.z), f2bf(v1.w) };
    *(u16x4*)&gwB[i]     = b0;
    *(u16x4*)&gwB[i + 4] = b1;
}

// ---------------------------------------------------------------------------
// K0b: spatial memory prep (round-13).
// ---------------------------------------------------------------------------
__global__ __launch_bounds__(256) void k_prep_mem(const float* __restrict__ sm,
                                                  u16* __restrict__ memHi,
                                                  u16* __restrict__ memT,
                                                  u16* __restrict__ memSH,
                                                  u16* __restrict__ memSL)
{
    const int idx = blockIdx.x * 256 + threadIdx.x;   // 16384 total
    const int m  = idx >> 8;
    const int h0 = (idx & 255) * 4;
    f4 v = {0.f, 0.f, 0.f, 0.f};
    if (m < MEMN) v = *(const f4*)&sm[(size_t)m * HD + h0];
    u16x4 hi = { f2bf(v.x), f2bf(v.y), f2bf(v.z), f2bf(v.w) };
    f4 hv = { bf2f(hi.x), bf2f(hi.y), bf2f(hi.z), bf2f(hi.w) };
    f4 lv = v - hv;
    u16x4 lo = { f2bf(lv.x), f2bf(lv.y), f2bf(lv.z), f2bf(lv.w) };
    *(u16x4*)&memHi[(size_t)m * HD + h0] = hi;
    memT[(size_t)(h0 + 0) * 64 + m] = hi.x;
    memT[(size_t)(h0 + 1) * 64 + m] = hi.y;
    memT[(size_t)(h0 + 2) * 64 + m] = hi.z;
    memT[(size_t)(h0 + 3) * 64 + m] = hi.w;
    const int p = h0 >> 6, s = (h0 >> 3) & 7, e = h0 & 7;
    const size_t sw = (size_t)p * 4096 + m * 64 + ((s ^ (m & 7)) << 3) + e;
    *(u16x4*)&memSH[sw] = hi;
    *(u16x4*)&memSL[sw] = lo;
}

// ---------------------------------------------------------------------------
// K0d: MWmT[o][m] = (M @ Wm)(m,o) as bf16, [1024][64].  MFMA, 16 blocks.
// ---------------------------------------------------------------------------
__global__ __launch_bounds__(256) void k_mwm(const u16* __restrict__ memHi,
                                             const u16* __restrict__ gwB,
                                             u16* __restrict__ MWmT)
{
    const int tid = threadIdx.x, lane = tid & 63, w = tid >> 6;
    const int fr = lane & 15, fk = (lane >> 4) * 8, jr = (lane >> 4) * 4;
    const int ob = blockIdx.x * 64 + w * 16;       // o-base of this wave
    f32x4 acc[4] = {};
    for (int ks = 0; ks < 32; ++ks) {
        s16x8 b = *(const s16x8*)&gwB[(size_t)(ob + fr) * 2048 + 1024 + ks * 32 + fk];
        #pragma unroll
        for (int mt = 0; mt < 4; ++mt) {
            s16x8 a = *(const s16x8*)&memHi[(size_t)(mt * 16 + fr) * HD + ks * 32 + fk];
            acc[mt] = __builtin_amdgcn_mfma_f32_16x16x32_bf16(a, b, acc[mt], 0, 0, 0);
        }
    }
    #pragma unroll
    for (int mt = 0; mt < 4; ++mt)
        #pragma unroll
        for (int j = 0; j < 4; ++j)
            MWmT[(size_t)(ob + fr) * 64 + mt * 16 + jr + j] = f2bf(acc[mt][j]);
}

// ---------------------------------------------------------------------------
// K1: round-13 fused feats+sim+softmax (vmem-free MFMA section).
// ---------------------------------------------------------------------------
__global__ __launch_bounds__(256) void k_pre(
    const float* __restrict__ x, const float* __restrict__ pos,
    const u16* __restrict__ memSH, const u16* __restrict__ memSL,
    u16* __restrict__ featsB, u16* __restrict__ wBg)
{
    __shared__ u16 fHi[64 * PK];
    __shared__ u16 fLo[64 * PK];
    __shared__ u16 memH[2][64 * 64];
    __shared__ u16 memL[2][64 * 64];

    const int tid  = threadIdx.x;
    const int r0   = blockIdx.x * 64;
    const int lane = tid & 63, w = tid >> 6;
    const int fr   = lane & 15, sg = lane >> 4;
    const int fk   = sg * 8, jr = sg * 4;

    const int srow = tid >> 2;
    const int scol = (tid & 3) * 16;
    const int prow = (r0 + srow) % SEQL;
    const float* xrow = &x[(size_t)(r0 + srow) * HD];
    const float* prp  = &pos[(size_t)prow * HD];

    f4 xa[4], pa[4];
    #pragma unroll
    for (int i = 0; i < 4; ++i) {
        xa[i] = *(const f4*)&xrow[scol + i * 4];
        pa[i] = *(const f4*)&prp[scol + i * 4];
    }
    GLOAD_LDS16(memSH + tid * 8,        &memH[0][tid * 8]);
    GLOAD_LDS16(memSH + 2048 + tid * 8, &memH[0][2048 + tid * 8]);
    GLOAD_LDS16(memSL + tid * 8,        &memL[0][tid * 8]);
    GLOAD_LDS16(memSL + 2048 + tid * 8, &memL[0][2048 + tid * 8]);

    f32x4 acc[4] = {};

    for (int p = 0; p < 16; ++p) {
        const int b = p & 1;
        WAITV0;

        {
            f4 f0 = xa[0] + pa[0], f1 = xa[1] + pa[1];
            f4 f2 = xa[2] + pa[2], f3 = xa[3] + pa[3];
            u16x8 h0 = { f2bf(f0.x), f2bf(f0.y), f2bf(f0.z), f2bf(f0.w),
                         f2bf(f1.x), f2bf(f1.y), f2bf(f1.z), f2bf(f1.w) };
            u16x8 h1 = { f2bf(f2.x), f2bf(f2.y), f2bf(f2.z), f2bf(f2.w),
                         f2bf(f3.x), f2bf(f3.y), f2bf(f3.z), f2bf(f3.w) };
            *(u16x8*)&featsB[(size_t)(r0 + srow) * HD + p * 64 + scol]     = h0;
            *(u16x8*)&featsB[(size_t)(r0 + srow) * HD + p * 64 + scol + 8] = h1;
            f4 hv0 = { bf2f(h0[0]), bf2f(h0[1]), bf2f(h0[2]), bf2f(h0[3]) };
            f4 hv1 = { bf2f(h0[4]), bf2f(h0[5]), bf2f(h0[6]), bf2f(h0[7]) };
            f4 hv2 = { bf2f(h1[0]), bf2f(h1[1]), bf2f(h1[2]), bf2f(h1[3]) };
            f4 hv3 = { bf2f(h1[4]), bf2f(h1[5]), bf2f(h1[6]), bf2f(h1[7]) };
            f4 l0 = f0 - hv0, l1 = f1 - hv1, l2 = f2 - hv2, l3 = f3 - hv3;
            u16x8 lo0 = { f2bf(l0.x), f2bf(l0.y), f2bf(l0.z), f2bf(l0.w),
                          f2bf(l1.x), f2bf(l1.y), f2bf(l1.z), f2bf(l1.w) };
            u16x8 lo1 = { f2bf(l2.x), f2bf(l2.y), f2bf(l2.z), f2bf(l2.w),
                          f2bf(l3.x), f2bf(l3.y), f2bf(l3.z), f2bf(l3.w) };
            *(u16x8*)&fHi[srow * PK + scol]     = h0;
            *(u16x8*)&fHi[srow * PK + scol + 8] = h1;
            *(u16x8*)&fLo[srow * PK + scol]     = lo0;
            *(u16x8*)&fLo[srow * PK + scol + 8] = lo1;
        }
        LGKMFENCE;
        __builtin_amdgcn_s_barrier();

        if (p < 15) {
            const size_t mo = (size_t)(p + 1) * 4096;
            GLOAD_LDS16(memSH + mo + tid * 8,        &memH[b ^ 1][tid * 8]);
            GLOAD_LDS16(memSH + mo + 2048 + tid * 8, &memH[b ^ 1][2048 + tid * 8]);
            GLOAD_LDS16(memSL + mo + tid * 8,        &memL[b ^ 1][tid * 8]);
            GLOAD_LDS16(memSL + mo + 2048 + tid * 8, &memL[b ^ 1][2048 + tid * 8]);
            const int c = (p + 1) * 64 + scol;
            #pragma unroll
            for (int i = 0; i < 4; ++i) {
                xa[i] = *(const f4*)&xrow[c + i * 4];
                pa[i] = *(const f4*)&prp[c + i * 4];
            }
        }

        #pragma unroll
        for (int ks = 0; ks < 2; ++ks) {
            s16x8 aH = *(const s16x8*)&fHi[(16 * w + fr) * PK + ks * 32 + fk];
            s16x8 aL = *(const s16x8*)&fLo[(16 * w + fr) * PK + ks * 32 + fk];
            #pragma unroll
            for (int n = 0; n < 4; ++n) {
                const int m = n * 16 + fr;
                const int slot = ((ks * 4 + sg) ^ (m & 7)) * 8;
                s16x8 bH = *(const s16x8*)&memH[b][m * 64 + slot];
                s16x8 bL = *(const s16x8*)&memL[b][m * 64 + slot];
                acc[n] = __builtin_amdgcn_mfma_f32_16x16x32_bf16(aH, bH, acc[n], 0, 0, 0);
                acc[n] = __builtin_amdgcn_mfma_f32_16x16x32_bf16(aH, bL, acc[n], 0, 0, 0);
                acc[n] = __builtin_amdgcn_mfma_f32_16x16x32_bf16(aL, bH, acc[n], 0, 0, 0);
            }
        }
    }

    // softmax over m (50)
    #pragma unroll
    for (int j = 0; j < 4; ++j) {
        const int rg = r0 + 16 * w + jr + j;
        float v[4];
        float mx = -1e30f;
        #pragma unroll
        for (int n = 0; n < 4; ++n) {
            v[n] = acc[n][j];
            const int m = n * 16 + fr;
            if (m < MEMN) mx = fmaxf(mx, v[n]);
        }
        #pragma unroll
        for (int d = 1; d < 16; d <<= 1) mx = fmaxf(mx, __shfl_xor(mx, d));
        float e[4], s = 0.f;
        #pragma unroll
        for (int n = 0; n < 4; ++n) {
            const int m = n * 16 + fr;
            e[n] = (m < MEMN) ? __expf(v[n] - mx) : 0.f;
            s += e[n];
        }
        #pragma unroll
        for (int d = 1; d < 16; d <<= 1) s += __shfl_xor(s, d);
        const float inv = 1.f / s;
        #pragma unroll
        for (int n = 0; n < 4; ++n)
            wBg[(size_t)rg * 64 + n * 16 + fr] = f2bf(e[n] * inv); // 0 pad m>=50
    }
}

// ---------------------------------------------------------------------------
// K2: out = featsB + sigmoid([featsB|w]@[Wf;MWm] + b) * (w@M).
//     Round-12 best skeleton (K=1088, 34 tiles, BM=256, BN=128, BK=32,
//     8 waves 4Mx2N, 2 LDS buffers, 48 KB -> 3 blocks/CU) with ONE barrier
//     per step: WAITV0 (my tile-kt loads) -> barrier (publishes tile kt AND
//     proves all waves' MFMA kt-1 done -> buf^1's ds_reads retired) ->
//     stage(buf^1, kt+1) (race-free by the barrier argument) -> ds_read+MFMA.
//     34 barriers instead of 68.
// ---------------------------------------------------------------------------
__global__ __launch_bounds__(512) void k_gate_out(
    const u16* __restrict__ featsB, const u16* __restrict__ wBg,
    const u16* __restrict__ gwB, const u16* __restrict__ memT,
    const u16* __restrict__ MWmT, const float* __restrict__ gb,
    float* __restrict__ out)
{
    __shared__ u16 As[2][256 * 32];   // 2 x 16 KB
    __shared__ u16 Bs[2][128 * 32];   // 2 x 8 KB

    const int tid = threadIdx.x;
    int bid = blockIdx.x;
    bid = (bid & 7) * 200 + (bid >> 3);      // XCD swizzle (1600 % 8 == 0)
    const int mt = bid >> 3, nt = bid & 7;   // 200 x 8 tiles
    const int row0 = mt * 256, col0 = nt * 128;
    const int lane = tid & 63, wave = tid >> 6;
    const int wm = wave >> 1, wn = wave & 1; // 4M x 2N (64x64 each)
    const int fr = lane & 15, fk = (lane >> 4) * 8;

    f32x4 acc[4][4] = {};

    const int sr = tid >> 2;                 // staging row 0..127
    const int sc = (tid & 3) * 8;            // staging col (elements)

    auto stage = [&](int buf, int kt) {
        if (kt < 32) {
            const int k0 = kt * 32;
            GLOAD_LDS16(featsB + (size_t)(row0 + sr) * HD + k0 + sc,       &As[buf][tid * 8]);
            GLOAD_LDS16(featsB + (size_t)(row0 + 128 + sr) * HD + k0 + sc, &As[buf][4096 + tid * 8]);
            GLOAD_LDS16(gwB + (size_t)(col0 + sr) * 2048 + k0 + sc,        &Bs[buf][tid * 8]);
        } else {
            const int k0 = (kt - 32) * 32;
            GLOAD_LDS16(wBg + (size_t)(row0 + sr) * 64 + k0 + sc,          &As[buf][tid * 8]);
            GLOAD_LDS16(wBg + (size_t)(row0 + 128 + sr) * 64 + k0 + sc,    &As[buf][4096 + tid * 8]);
            GLOAD_LDS16(MWmT + (size_t)(col0 + sr) * 64 + k0 + sc,         &Bs[buf][tid * 8]);
        }
    };

    stage(0, 0);                             // 3 outstanding
    int cur = 0;

    for (int kt = 0; kt < 34; ++kt) {
        WAITV0;                              // my tile-kt loads in LDS
        __builtin_amdgcn_s_barrier();        // tile kt published; buf^1 free
        if (kt < 33) stage(cur ^ 1, kt + 1); // overlaps ds_read + MFMA below
        SCHB;

        s16x8 aF[4], bF[4];
        #pragma unroll
        for (int m = 0; m < 4; ++m)
            aF[m] = *(const s16x8*)&As[cur][(wm * 64 + m * 16 + fr) * 32 + fk];
        #pragma unroll
        for (int n = 0; n < 4; ++n)
            bF[n] = *(const s16x8*)&Bs[cur][(wn * 64 + n * 16 + fr) * 32 + fk];
        #pragma unroll
        for (int m = 0; m < 4; ++m)
            #pragma unroll
            for (int n = 0; n < 4; ++n)
                acc[m][n] = __builtin_amdgcn_mfma_f32_16x16x32_bf16(
                    aF[m], bF[n], acc[m][n], 0, 0, 0);

        cur ^= 1;
    }

    // epilogue: accR = w@M per (m,n); out = feats + sigmoid(acc+b)*accR
    #pragma unroll
    for (int m = 0; m < 4; ++m) {
        const size_t ab = (size_t)(row0 + wm * 64 + m * 16 + fr) * 64 + fk;
        s16x8 a2_0 = *(const s16x8*)&wBg[ab];
        s16x8 a2_1 = *(const s16x8*)&wBg[ab + 32];
        #pragma unroll
        for (int n = 0; n < 4; ++n) {
            const size_t cb = (size_t)(col0 + wn * 64 + n * 16 + fr) * 64 + fk;
            s16x8 bT0 = *(const s16x8*)&memT[cb];
            s16x8 bT1 = *(const s16x8*)&memT[cb + 32];
            f32x4 accR = {};
            accR = __builtin_amdgcn_mfma_f32_16x16x32_bf16(a2_0, bT0, accR, 0, 0, 0);
            accR = __builtin_amdgcn_mfma_f32_16x16x32_bf16(a2_1, bT1, accR, 0, 0, 0);

            const int crow = row0 + wm * 64 + m * 16 + (lane >> 4) * 4;
            const int ccol = col0 + wn * 64 + n * 16 + fr;
            const float bias = gb[ccol];
            #pragma unroll
            for (int j = 0; j < 4; ++j) {
                const size_t idx = (size_t)(crow + j) * HD + ccol;
                const float fe = bf2f(featsB[idx]);
                const float pre = acc[m][n][j] + bias;
                const float g = 1.0f / (1.0f + __expf(-pre));
                out[idx] = fe + g * accR[j];
            }
        }
    }
}

// ---------------------------------------------------------------------------
extern "C" void kernel_launch(void* const* d_in, const int* in_sizes, int n_in,
                              void* d_out, int out_size, void* d_ws, size_t ws_size,
                              hipStream_t stream)
{
    const float* x   = (const float*)d_in[0];
    const float* sm  = (const float*)d_in[1];
    const float* pos = (const float*)d_in[2];
    const float* gw  = (const float*)d_in[3];
    const float* gb  = (const float*)d_in[4];
    float* out = (float*)d_out;

    u16* featsB = (u16*)d_ws;                          // 51200*1024 (100 MB)
    u16* gwB    = featsB + (size_t)RTOT * HD;          // 1024*2048
    u16* wBg    = gwB + (size_t)HD * 2048;             // 51200*64
    u16* memHi  = wBg + (size_t)RTOT * 64;             // 64*1024
    u16* memT   = memHi + 64 * HD;                     // 1024*64
    u16* MWmT   = memT + (size_t)HD * 64;              // 1024*64
    u16* memSH  = MWmT + (size_t)HD * 64;              // 16*64*64 swizzled
    u16* memSL  = memSH + (size_t)64 * HD;             // 16*64*64 swizzled

    k_cvt_w<<<dim3(1024), dim3(256), 0, stream>>>(gw, gwB);
    k_prep_mem<<<dim3(64), dim3(256), 0, stream>>>(sm, memHi, memT, memSH, memSL);
    k_mwm<<<dim3(16), dim3(256), 0, stream>>>(memHi, gwB, MWmT);
    k_pre<<<dim3(RTOT / 64), dim3(256), 0, stream>>>(x, pos, memSH, memSL,
                                                     featsB, wBg);
    k_gate_out<<<dim3(1600), dim3(512), 0, stream>>>(featsB, wBg, gwB, memT,
                                                     MWmT, gb, out);
}

// Round 19
// 368.947 us; speedup vs baseline: 16.7643x; 1.1265x over previous
//
#include <hip/hip_runtime.h>
#include <cstdint>
#include <cstddef>

#define HD   1024
#define SEQL 200
#define MEMN 50
#define RTOT 51200   // 256 * 200
#define PK   72      // fHi/fLo row stride (64 + 8 pad -> 2-way banks, free)

typedef float  f4    __attribute__((ext_vector_type(4)));
typedef float  f32x4 __attribute__((ext_vector_type(4)));
typedef short  s16x8 __attribute__((ext_vector_type(8)));
typedef unsigned short u16;
typedef unsigned short u16x4 __attribute__((ext_vector_type(4)));
typedef unsigned short u16x8 __attribute__((ext_vector_type(8)));

__device__ __forceinline__ u16 f2bf(float f) {
    unsigned u = __builtin_bit_cast(unsigned, f);
    u += 0x7FFFu + ((u >> 16) & 1u);          // RNE
    return (u16)(u >> 16);
}
__device__ __forceinline__ float bf2f(u16 h) {
    unsigned u = ((unsigned)h) << 16;
    return __builtin_bit_cast(float, u);
}

#define GLOAD_LDS16(g, l) __builtin_amdgcn_global_load_lds( \
    (const __attribute__((address_space(1))) unsigned int*)(g), \
    (__attribute__((address_space(3))) unsigned int*)(l), 16, 0, 0)

#define WAITV3 asm volatile("s_waitcnt vmcnt(3)" ::: "memory")
#define WAITV0 asm volatile("s_waitcnt vmcnt(0)" ::: "memory")
#define LGKMFENCE asm volatile("s_waitcnt lgkmcnt(0)" ::: "memory")
#define SCHB   __builtin_amdgcn_sched_barrier(0)

// ---------------------------------------------------------------------------
// K0a: gate_w f32 -> bf16, layout [o][2048] k-contig. Wf = cols 0..1023,
//      Wm = cols 1024..2047.
// ---------------------------------------------------------------------------
__global__ __launch_bounds__(256) void k_cvt_w(const float* __restrict__ gw,
                                               u16* __restrict__ gwB)
{
    const size_t i = ((size_t)blockIdx.x * 256 + threadIdx.x) * 8;
    f4 v0 = *(const f4*)&gw[i];
    f4 v1 = *(const f4*)&gw[i + 4];
    u16x4 b0 = { f2bf(v0.x), f2bf(v0.y), f2bf(v0.z), f2bf(v0.w) };
    u16x4 b1 = { f2bf(v1.x), f2bf(v1.y), f2bf(v1.z), f2bf(v1.w) };
    *(u16x4*)&gwB[i]     = b0;
    *(u16x4*)&gwB[i + 4] = b1;
}

// ---------------------------------------------------------------------------
// K0b: spatial memory prep.
//   memHi  [64][1024] bf16 linear (rows 50..63 zero)  — for k_mwm
//   memT   [1024][64] bf16 transposed                  — for k_gate epilogue
//   memSH/memSL [16][64][8slots][8] bf16, slot pre-swizzled s^(m&7)
//                                                      — for k_pre LDS staging
// ---------------------------------------------------------------------------
__global__ __launch_bounds__(256) void k_prep_mem(const float* __restrict__ sm,
                                                  u16* __restrict__ memHi,
                                                  u16* __restrict__ memT,
                                                  u16* __restrict__ memSH,
                                                  u16* __restrict__ memSL)
{
    const int idx = blockIdx.x * 256 + threadIdx.x;   // 16384 total
    const int m  = idx >> 8;
    const int h0 = (idx & 255) * 4;
    f4 v = {0.f, 0.f, 0.f, 0.f};
    if (m < MEMN) v = *(const f4*)&sm[(size_t)m * HD + h0];
    u16x4 hi = { f2bf(v.x), f2bf(v.y), f2bf(v.z), f2bf(v.w) };
    f4 hv = { bf2f(hi.x), bf2f(hi.y), bf2f(hi.z), bf2f(hi.w) };
    f4 lv = v - hv;
    u16x4 lo = { f2bf(lv.x), f2bf(lv.y), f2bf(lv.z), f2bf(lv.w) };
    *(u16x4*)&memHi[(size_t)m * HD + h0] = hi;
    memT[(size_t)(h0 + 0) * 64 + m] = hi.x;
    memT[(size_t)(h0 + 1) * 64 + m] = hi.y;
    memT[(size_t)(h0 + 2) * 64 + m] = hi.z;
    memT[(size_t)(h0 + 3) * 64 + m] = hi.w;
    // swizzled copies: panel p = h0>>6, slot s = (h0>>3)&7, elem e = h0&7
    const int p = h0 >> 6, s = (h0 >> 3) & 7, e = h0 & 7;
    const size_t sw = (size_t)p * 4096 + m * 64 + ((s ^ (m & 7)) << 3) + e;
    *(u16x4*)&memSH[sw] = hi;
    *(u16x4*)&memSL[sw] = lo;
}

// ---------------------------------------------------------------------------
// K0d: MWmT[o][m] = (M @ Wm)(m,o) as bf16, [1024][64].  MFMA, 16 blocks.
// ---------------------------------------------------------------------------
__global__ __launch_bounds__(256) void k_mwm(const u16* __restrict__ memHi,
                                             const u16* __restrict__ gwB,
                                             u16* __restrict__ MWmT)
{
    const int tid = threadIdx.x, lane = tid & 63, w = tid >> 6;
    const int fr = lane & 15, fk = (lane >> 4) * 8, jr = (lane >> 4) * 4;
    const int ob = blockIdx.x * 64 + w * 16;       // o-base of this wave
    f32x4 acc[4] = {};
    for (int ks = 0; ks < 32; ++ks) {
        s16x8 b = *(const s16x8*)&gwB[(size_t)(ob + fr) * 2048 + 1024 + ks * 32 + fk];
        #pragma unroll
        for (int mt = 0; mt < 4; ++mt) {
            s16x8 a = *(const s16x8*)&memHi[(size_t)(mt * 16 + fr) * HD + ks * 32 + fk];
            acc[mt] = __builtin_amdgcn_mfma_f32_16x16x32_bf16(a, b, acc[mt], 0, 0, 0);
        }
    }
    #pragma unroll
    for (int mt = 0; mt < 4; ++mt)
        #pragma unroll
        for (int j = 0; j < 4; ++j)
            MWmT[(size_t)(ob + fr) * 64 + mt * 16 + jr + j] = f2bf(acc[mt][j]);
}

// ---------------------------------------------------------------------------
// K1: fused feats+sim+softmax, vmem-free MFMA section.
//   feats = x + pos (f32); featsB = bf16(feats); lo = bf16(feats - hi);
//   sim = feats(hi/lo) @ M(hi/lo)^T (3-pass, lo*lo dropped); softmax -> wBg.
//   64 rows/block, 4 waves, KP=64 (16 panels). Mem panel (hi+lo, 16 KB)
//   double-buffered in LDS via gload_lds from pre-swizzled memSH/memSL.
//   Per panel: WAITV0 -> convert -> lgkm0 -> s_barrier (publish mem(p);
//   all waves done reading other buf) -> issue mem(p+1)+x(p+1) -> MFMA(DS).
// ---------------------------------------------------------------------------
__global__ __launch_bounds__(256) void k_pre(
    const float* __restrict__ x, const float* __restrict__ pos,
    const u16* __restrict__ memSH, const u16* __restrict__ memSL,
    u16* __restrict__ featsB, u16* __restrict__ wBg)
{
    __shared__ u16 fHi[64 * PK];        // 9.2 KB
    __shared__ u16 fLo[64 * PK];        // 9.2 KB
    __shared__ u16 memH[2][64 * 64];    // 16 KB
    __shared__ u16 memL[2][64 * 64];    // 16 KB   (total 50.4 KB -> 3 blk/CU)

    const int tid  = threadIdx.x;
    const int r0   = blockIdx.x * 64;
    const int lane = tid & 63, w = tid >> 6;
    const int fr   = lane & 15, sg = lane >> 4;
    const int fk   = sg * 8, jr = sg * 4;

    const int srow = tid >> 2;          // wave-exclusive rows 16w..16w+15
    const int scol = (tid & 3) * 16;    // 16 contiguous cols per thread
    const int prow = (r0 + srow) % SEQL;
    const float* xrow = &x[(size_t)(r0 + srow) * HD];
    const float* prp  = &pos[(size_t)prow * HD];

    f4 xa[4], pa[4];
    #pragma unroll
    for (int i = 0; i < 4; ++i) {
        xa[i] = *(const f4*)&xrow[scol + i * 4];
        pa[i] = *(const f4*)&prp[scol + i * 4];
    }
    // prologue: mem panel 0 -> buf 0 (cooperative, linear dest)
    GLOAD_LDS16(memSH + tid * 8,        &memH[0][tid * 8]);
    GLOAD_LDS16(memSH + 2048 + tid * 8, &memH[0][2048 + tid * 8]);
    GLOAD_LDS16(memSL + tid * 8,        &memL[0][tid * 8]);
    GLOAD_LDS16(memSL + 2048 + tid * 8, &memL[0][2048 + tid * 8]);

    f32x4 acc[4] = {};                  // sim[16 rows][m = n*16 + fr]

    for (int p = 0; p < 16; ++p) {
        const int b = p & 1;
        WAITV0;                         // x(p) + my mem(p) portions retired

        // ---- convert panel p: regs -> fHi/fLo LDS + featsB store ----
        {
            f4 f0 = xa[0] + pa[0], f1 = xa[1] + pa[1];
            f4 f2 = xa[2] + pa[2], f3 = xa[3] + pa[3];
            u16x8 h0 = { f2bf(f0.x), f2bf(f0.y), f2bf(f0.z), f2bf(f0.w),
                         f2bf(f1.x), f2bf(f1.y), f2bf(f1.z), f2bf(f1.w) };
            u16x8 h1 = { f2bf(f2.x), f2bf(f2.y), f2bf(f2.z), f2bf(f2.w),
                         f2bf(f3.x), f2bf(f3.y), f2bf(f3.z), f2bf(f3.w) };
            *(u16x8*)&featsB[(size_t)(r0 + srow) * HD + p * 64 + scol]     = h0;
            *(u16x8*)&featsB[(size_t)(r0 + srow) * HD + p * 64 + scol + 8] = h1;
            f4 hv0 = { bf2f(h0[0]), bf2f(h0[1]), bf2f(h0[2]), bf2f(h0[3]) };
            f4 hv1 = { bf2f(h0[4]), bf2f(h0[5]), bf2f(h0[6]), bf2f(h0[7]) };
            f4 hv2 = { bf2f(h1[0]), bf2f(h1[1]), bf2f(h1[2]), bf2f(h1[3]) };
            f4 hv3 = { bf2f(h1[4]), bf2f(h1[5]), bf2f(h1[6]), bf2f(h1[7]) };
            f4 l0 = f0 - hv0, l1 = f1 - hv1, l2 = f2 - hv2, l3 = f3 - hv3;
            u16x8 lo0 = { f2bf(l0.x), f2bf(l0.y), f2bf(l0.z), f2bf(l0.w),
                          f2bf(l1.x), f2bf(l1.y), f2bf(l1.z), f2bf(l1.w) };
            u16x8 lo1 = { f2bf(l2.x), f2bf(l2.y), f2bf(l2.z), f2bf(l2.w),
                          f2bf(l3.x), f2bf(l3.y), f2bf(l3.z), f2bf(l3.w) };
            *(u16x8*)&fHi[srow * PK + scol]     = h0;
            *(u16x8*)&fHi[srow * PK + scol + 8] = h1;
            *(u16x8*)&fLo[srow * PK + scol]     = lo0;
            *(u16x8*)&fLo[srow * PK + scol + 8] = lo1;
        }
        LGKMFENCE;                      // wave-lockstep: whole wave's ds_writes done
        __builtin_amdgcn_s_barrier();   // publish mem(p); all done reading buf b^1

        // ---- issue next panel's mem staging + x/pos prefetch ----
        if (p < 15) {
            const size_t mo = (size_t)(p + 1) * 4096;
            GLOAD_LDS16(memSH + mo + tid * 8,        &memH[b ^ 1][tid * 8]);
            GLOAD_LDS16(memSH + mo + 2048 + tid * 8, &memH[b ^ 1][2048 + tid * 8]);
            GLOAD_LDS16(memSL + mo + tid * 8,        &memL[b ^ 1][tid * 8]);
            GLOAD_LDS16(memSL + mo + 2048 + tid * 8, &memL[b ^ 1][2048 + tid * 8]);
            const int c = (p + 1) * 64 + scol;
            #pragma unroll
            for (int i = 0; i < 4; ++i) {
                xa[i] = *(const f4*)&xrow[c + i * 4];
                pa[i] = *(const f4*)&prp[c + i * 4];
            }
        }

        // ---- sim MFMA: pure DS (fHi/fLo + swizzled mem panel) ----
        #pragma unroll
        for (int ks = 0; ks < 2; ++ks) {
            s16x8 aH = *(const s16x8*)&fHi[(16 * w + fr) * PK + ks * 32 + fk];
            s16x8 aL = *(const s16x8*)&fLo[(16 * w + fr) * PK + ks * 32 + fk];
            #pragma unroll
            for (int n = 0; n < 4; ++n) {
                const int m = n * 16 + fr;
                const int slot = ((ks * 4 + sg) ^ (m & 7)) * 8;
                s16x8 bH = *(const s16x8*)&memH[b][m * 64 + slot];
                s16x8 bL = *(const s16x8*)&memL[b][m * 64 + slot];
                acc[n] = __builtin_amdgcn_mfma_f32_16x16x32_bf16(aH, bH, acc[n], 0, 0, 0);
                acc[n] = __builtin_amdgcn_mfma_f32_16x16x32_bf16(aH, bL, acc[n], 0, 0, 0);
                acc[n] = __builtin_amdgcn_mfma_f32_16x16x32_bf16(aL, bH, acc[n], 0, 0, 0);
            }
        }
    }

    // softmax over m (50)
    #pragma unroll
    for (int j = 0; j < 4; ++j) {
        const int rg = r0 + 16 * w + jr + j;
        float v[4];
        float mx = -1e30f;
        #pragma unroll
        for (int n = 0; n < 4; ++n) {
            v[n] = acc[n][j];
            const int m = n * 16 + fr;
            if (m < MEMN) mx = fmaxf(mx, v[n]);
        }
        #pragma unroll
        for (int d = 1; d < 16; d <<= 1) mx = fmaxf(mx, __shfl_xor(mx, d));
        float e[4], s = 0.f;
        #pragma unroll
        for (int n = 0; n < 4; ++n) {
            const int m = n * 16 + fr;
            e[n] = (m < MEMN) ? __expf(v[n] - mx) : 0.f;
            s += e[n];
        }
        #pragma unroll
        for (int d = 1; d < 16; d <<= 1) s += __shfl_xor(s, d);
        const float inv = 1.f / s;
        #pragma unroll
        for (int n = 0; n < 4; ++n)
            wBg[(size_t)rg * 64 + n * 16 + fr] = f2bf(e[n] * inv); // 0 pad m>=50
    }
}

// ---------------------------------------------------------------------------
// K2: out = featsB + sigmoid([featsB|w]@[Wf;MWm] + b) * (w@M).
//     Measured-best: K=1088 (34 tiles). BM=256, BN=128, BK=32, 8 waves
//     (4Mx2N, 512 thr). 2 LDS buffers dist-1 (48 KB -> 3 blocks/CU),
//     stage-before-wait + counted vmcnt(3). accR = w@M per-(m,n) in epilogue.
// ---------------------------------------------------------------------------
__global__ __launch_bounds__(512) void k_gate_out(
    const u16* __restrict__ featsB, const u16* __restrict__ wBg,
    const u16* __restrict__ gwB, const u16* __restrict__ memT,
    const u16* __restrict__ MWmT, const float* __restrict__ gb,
    float* __restrict__ out)
{
    __shared__ u16 As[2][256 * 32];   // 2 x 16 KB
    __shared__ u16 Bs[2][128 * 32];   // 2 x 8 KB

    const int tid = threadIdx.x;
    int bid = blockIdx.x;
    bid = (bid & 7) * 200 + (bid >> 3);      // XCD swizzle (1600 % 8 == 0)
    const int mt = bid >> 3, nt = bid & 7;   // 200 x 8 tiles
    const int row0 = mt * 256, col0 = nt * 128;
    const int lane = tid & 63, wave = tid >> 6;
    const int wm = wave >> 1, wn = wave & 1; // 4M x 2N (64x64 each)
    const int fr = lane & 15, fk = (lane >> 4) * 8;

    f32x4 acc[4][4] = {};

    const int sr = tid >> 2;                 // staging row 0..127
    const int sc = (tid & 3) * 8;            // staging col (elements)

    auto stage = [&](int buf, int kt) {
        if (kt < 32) {
            const int k0 = kt * 32;
            GLOAD_LDS16(featsB + (size_t)(row0 + sr) * HD + k0 + sc,       &As[buf][tid * 8]);
            GLOAD_LDS16(featsB + (size_t)(row0 + 128 + sr) * HD + k0 + sc, &As[buf][4096 + tid * 8]);
            GLOAD_LDS16(gwB + (size_t)(col0 + sr) * 2048 + k0 + sc,        &Bs[buf][tid * 8]);
        } else {
            const int k0 = (kt - 32) * 32;
            GLOAD_LDS16(wBg + (size_t)(row0 + sr) * 64 + k0 + sc,          &As[buf][tid * 8]);
            GLOAD_LDS16(wBg + (size_t)(row0 + 128 + sr) * 64 + k0 + sc,    &As[buf][4096 + tid * 8]);
            GLOAD_LDS16(MWmT + (size_t)(col0 + sr) * 64 + k0 + sc,         &Bs[buf][tid * 8]);
        }
    };

    stage(0, 0);
    int cur = 0;

    for (int kt = 0; kt < 34; ++kt) {
        if (kt < 33) {
            stage(cur ^ 1, kt + 1);
            WAITV3;                          // cur's 3 loads done
        } else {
            WAITV0;
        }
        __builtin_amdgcn_s_barrier();
        SCHB;

        s16x8 aF[4], bF[4];
        #pragma unroll
        for (int m = 0; m < 4; ++m)
            aF[m] = *(const s16x8*)&As[cur][(wm * 64 + m * 16 + fr) * 32 + fk];
        #pragma unroll
        for (int n = 0; n < 4; ++n)
            bF[n] = *(const s16x8*)&Bs[cur][(wn * 64 + n * 16 + fr) * 32 + fk];
        #pragma unroll
        for (int m = 0; m < 4; ++m)
            #pragma unroll
            for (int n = 0; n < 4; ++n)
                acc[m][n] = __builtin_amdgcn_mfma_f32_16x16x32_bf16(
                    aF[m], bF[n], acc[m][n], 0, 0, 0);

        SCHB;
        __builtin_amdgcn_s_barrier();
        cur ^= 1;
    }

    // epilogue: accR = w@M per (m,n); out = feats + sigmoid(acc+b)*accR
    #pragma unroll
    for (int m = 0; m < 4; ++m) {
        const size_t ab = (size_t)(row0 + wm * 64 + m * 16 + fr) * 64 + fk;
        s16x8 a2_0 = *(const s16x8*)&wBg[ab];
        s16x8 a2_1 = *(const s16x8*)&wBg[ab + 32];
        #pragma unroll
        for (int n = 0; n < 4; ++n) {
            const size_t cb = (size_t)(col0 + wn * 64 + n * 16 + fr) * 64 + fk;
            s16x8 bT0 = *(const s16x8*)&memT[cb];
            s16x8 bT1 = *(const s16x8*)&memT[cb + 32];
            f32x4 accR = {};
            accR = __builtin_amdgcn_mfma_f32_16x16x32_bf16(a2_0, bT0, accR, 0, 0, 0);
            accR = __builtin_amdgcn_mfma_f32_16x16x32_bf16(a2_1, bT1, accR, 0, 0, 0);

            const int crow = row0 + wm * 64 + m * 16 + (lane >> 4) * 4;
            const int ccol = col0 + wn * 64 + n * 16 + fr;
            const float bias = gb[ccol];
            #pragma unroll
            for (int j = 0; j < 4; ++j) {
                const size_t idx = (size_t)(crow + j) * HD + ccol;
                const float fe = bf2f(featsB[idx]);
                const float pre = acc[m][n][j] + bias;
                const float g = 1.0f / (1.0f + __expf(-pre));
                out[idx] = fe + g * accR[j];
            }
        }
    }
}

// ---------------------------------------------------------------------------
extern "C" void kernel_launch(void* const* d_in, const int* in_sizes, int n_in,
                              void* d_out, int out_size, void* d_ws, size_t ws_size,
                              hipStream_t stream)
{
    const float* x   = (const float*)d_in[0];
    const float* sm  = (const float*)d_in[1];
    const float* pos = (const float*)d_in[2];
    const float* gw  = (const float*)d_in[3];
    const float* gb  = (const float*)d_in[4];
    float* out = (float*)d_out;

    u16* featsB = (u16*)d_ws;                          // 51200*1024 (100 MB)
    u16* gwB    = featsB + (size_t)RTOT * HD;          // 1024*2048
    u16* wBg    = gwB + (size_t)HD * 2048;             // 51200*64
    u16* memHi  = wBg + (size_t)RTOT * 64;             // 64*1024
    u16* memT   = memHi + 64 * HD;                     // 1024*64
    u16* MWmT   = memT + (size_t)HD * 64;              // 1024*64
    u16* memSH  = MWmT + (size_t)HD * 64;              // 16*64*64 swizzled
    u16* memSL  = memSH + (size_t)64 * HD;             // 16*64*64 swizzled

    k_cvt_w<<<dim3(1024), dim3(256), 0, stream>>>(gw, gwB);
    k_prep_mem<<<dim3(64), dim3(256), 0, stream>>>(sm, memHi, memT, memSH, memSL);
    k_mwm<<<dim3(16), dim3(256), 0, stream>>>(memHi, gwB, MWmT);
    k_pre<<<dim3(RTOT / 64), dim3(256), 0, stream>>>(x, pos, memSH, memSL,
                                                     featsB, wBg);
    k_gate_out<<<dim3(1600), dim3(512), 0, stream>>>(featsB, wBg, gwB, memT,
                                                     MWmT, gb, out);
}